// Round 6
// baseline (625.708 us; speedup 1.0000x reference)
//
#include <hip/hip_runtime.h>
#include <hip/hip_bf16.h>
#include <hip/hip_cooperative_groups.h>

namespace cg = cooperative_groups;

#define NN 8192
#define EE 262144
#define DD 128
#define HH 64
#define NB 1024            // cooperative grid: 4 blocks/CU on 256 CUs
#define NT 256

typedef float f32x4 __attribute__((ext_vector_type(4)));   // native vec for nontemporal

// One cooperative kernel.
// Phase 1: precompute Pt[n][j]=embed[n].W1[0:128,j], Pb[n][j]=embed[n].W1[128:256,j]
//          (8 nodes/block) + zero-fill the 268 MB output with NONTEMPORAL stores
//          (so Pt/Pb stay L2-resident for phase 2).
// grid.sync()
// Phase 2: per edge (256/block, 16 lanes each): decode ei, gather Pt[r]/Pb[c]
//          from L2, 16-lane reduce, gate = u/(u+(1-u)e^-la), scatter atomics.
//          adj[r][c]==1 by construction for listed edges; the transpose term is
//          gated on adj[c][r] (nonzero ~0.4% of edges).
__global__ void __launch_bounds__(NT, 4) fused_kernel(
    const float* __restrict__ embed,
    const float* __restrict__ adj,
    const float* __restrict__ noise,
    const float* __restrict__ W1,
    const float* __restrict__ b1,
    const float* __restrict__ W2,
    const float* __restrict__ b2,
    const int*   __restrict__ ei,
    float* __restrict__ Pt,
    float* __restrict__ Pb,
    float* __restrict__ out)
{
    const int tid  = threadIdx.x;
    const int b    = blockIdx.x;
    const int w    = tid >> 6;
    const int lane = tid & 63;

    __shared__ float esh[4][DD];
    __shared__ int   sflag;

    // int64/int32 edge_index layout detect: int64 has all-zero high words.
    if (tid < 64) {
        int v = ei[2 * tid + 1];
        unsigned long long bal = __ballot(v != 0);
        if (tid == 0) sflag = (bal == 0ULL) ? 1 : 0;
    }

    // ---------------- Phase 1a: precompute (8 nodes per block) ----------------
#pragma unroll 1
    for (int it = 0; it < 2; ++it) {
        const int n = (b << 3) + (it << 2) + w;
        __syncthreads();
        esh[w][lane]      = embed[n * DD + lane];
        esh[w][lane + 64] = embed[n * DD + 64 + lane];
        __syncthreads();
        float at = 0.f, ab = 0.f;
#pragma unroll 8
        for (int k = 0; k < DD; ++k) {
            const float ek = esh[w][k];
            at = fmaf(ek, W1[k * HH + lane],        at);   // 256 B coalesced
            ab = fmaf(ek, W1[(DD + k) * HH + lane], ab);
        }
        Pt[n * HH + lane] = at;
        Pb[n * HH + lane] = ab;
    }

    // ---------------- Phase 1b: nontemporal zero-fill (256 MB) ----------------
    {
        f32x4* out4 = (f32x4*)out;
        const f32x4 z = {0.f, 0.f, 0.f, 0.f};
        const size_t base = (size_t)b * (64 * NT) + tid;
#pragma unroll
        for (int i = 0; i < 64; ++i)
            __builtin_nontemporal_store(z, &out4[base + (size_t)i * NT]);
    }

    cg::this_grid().sync();

    // ---------------- Phase 2: gate + scatter (256 edges per block) -----------
    const bool i64 = (sflag != 0);
    const int q    = lane & 15;                  // hidden quad 0..15
    const int grp  = (w << 2) + (lane >> 4);     // 16-lane group id 0..15

    const float4 bb    = ((const float4*)b1)[q];
    const float4 ww    = ((const float4*)W2)[q];
    const float  bias2 = b2[0];
    const float4* Pt4  = (const float4*)Pt;
    const float4* Pb4  = (const float4*)Pb;

#pragma unroll 1
    for (int p = 0; p < 4; ++p) {
        const int ebase = (b << 8) + (p << 6) + (grp << 2);

        int r[4], c[4];
        if (i64) {
            const int4 r0 = ((const int4*)ei)[(ebase >> 1)];
            const int4 r1 = ((const int4*)ei)[(ebase >> 1) + 1];
            const int4 c0 = ((const int4*)(ei + 2 * EE))[(ebase >> 1)];
            const int4 c1 = ((const int4*)(ei + 2 * EE))[(ebase >> 1) + 1];
            r[0] = r0.x; r[1] = r0.z; r[2] = r1.x; r[3] = r1.z;
            c[0] = c0.x; c[1] = c0.z; c[2] = c1.x; c[3] = c1.z;
        } else {
            const int4 rr = ((const int4*)ei)[ebase >> 2];
            const int4 cc = ((const int4*)(ei + EE))[ebase >> 2];
            r[0] = rr.x; r[1] = rr.y; r[2] = rr.z; r[3] = rr.w;
            c[0] = cc.x; c[1] = cc.y; c[2] = cc.z; c[3] = cc.w;
        }

        // Leaders issue the slow random loads EARLY (hide under gather+reduce).
        float u[4], a[4];
        if (q == 0) {
            const float4 un = ((const float4*)noise)[ebase >> 2];
            u[0] = un.x; u[1] = un.y; u[2] = un.z; u[3] = un.w;
#pragma unroll
            for (int i = 0; i < 4; ++i)
                a[i] = adj[(size_t)c[i] * NN + r[i]];
        }

        float v[4];
#pragma unroll
        for (int i = 0; i < 4; ++i) {
            const float4 pt = Pt4[r[i] * 16 + q];
            const float4 pb = Pb4[c[i] * 16 + q];
            v[i] = fmaxf(pt.x + pb.x + bb.x, 0.f) * ww.x
                 + fmaxf(pt.y + pb.y + bb.y, 0.f) * ww.y
                 + fmaxf(pt.z + pb.z + bb.z, 0.f) * ww.z
                 + fmaxf(pt.w + pb.w + bb.w, 0.f) * ww.w;
        }

#pragma unroll
        for (int i = 0; i < 4; ++i)
#pragma unroll
            for (int off = 8; off; off >>= 1)
                v[i] += __shfl_xor(v[i], off, 64);

        if (q == 0) {
#pragma unroll
            for (int i = 0; i < 4; ++i) {
                const float la = v[i] + bias2;
                // sigmoid(log u - log1p(-u) + la) = u / (u + (1-u) e^{-la})
                const float ex = __expf(-la);
                const float g2 = 0.5f * u[i] / (u[i] + (1.f - u[i]) * ex);
                atomicAdd(&out[(size_t)r[i] * NN + c[i]], g2);   // adj==1 here
                if (a[i] != 0.f)
                    atomicAdd(&out[(size_t)c[i] * NN + r[i]], g2 * a[i]);
            }
        }
    }
}

extern "C" void kernel_launch(void* const* d_in, const int* in_sizes, int n_in,
                              void* d_out, int out_size, void* d_ws, size_t ws_size,
                              hipStream_t stream) {
    const float* embed = (const float*)d_in[0];
    const float* adj   = (const float*)d_in[1];
    const float* noise = (const float*)d_in[2];
    const float* W1    = (const float*)d_in[3];
    const float* b1    = (const float*)d_in[4];
    const float* W2    = (const float*)d_in[5];
    const float* b2    = (const float*)d_in[6];
    const int*   ei    = (const int*)d_in[7];
    float* out = (float*)d_out;

    float* Pt = (float*)d_ws;                    // 2 MB
    float* Pb = Pt + (size_t)NN * HH;            // 2 MB

    void* args[] = {(void*)&embed, (void*)&adj, (void*)&noise, (void*)&W1,
                    (void*)&b1, (void*)&W2, (void*)&b2, (void*)&ei,
                    (void*)&Pt, (void*)&Pb, (void*)&out};
    (void)hipLaunchCooperativeKernel(reinterpret_cast<void*>(fused_kernel),
                                     dim3(NB), dim3(NT), args, 0, stream);
}

// Round 7
// 446.368 us; speedup vs baseline: 1.4018x; 1.4018x over previous
//
#include <hip/hip_runtime.h>
#include <hip/hip_bf16.h>

#define NN 8192
#define EE 262144
#define DD 128
#define HH 64

#define PRE_BLOCKS  2048                 // 4 nodes each
#define FILL_BLOCKS 8192                 // 2048 float4 (32 KB) of zeros each
#define EPW 16                           // edges per wave (4 per 16-lane group)

// Heterogeneous init: blocks [0, PRE_BLOCKS) precompute
//   Pt[n][j] = embed[n] . W1[0:128, j],  Pb[n][j] = embed[n] . W1[128:256, j]
// (dispatched first so their FMA tails hide under the fill's BW);
// blocks [PRE_BLOCKS, PRE_BLOCKS+FILL_BLOCKS) zero the 268 MB output with
// normal write-back stores (NT stores measured 5x slower in round 6).
__global__ void init_kernel(const float* __restrict__ embed,
                            const float* __restrict__ W1,
                            float* __restrict__ Pt,
                            float* __restrict__ Pb,
                            float4* __restrict__ out4) {
    const int tid = threadIdx.x;
    const int b   = blockIdx.x;

    if (b >= PRE_BLOCKS) {
        const size_t base = (size_t)(b - PRE_BLOCKS) * 2048 + tid;
        const float4 z = make_float4(0.f, 0.f, 0.f, 0.f);
#pragma unroll
        for (int i = 0; i < 8; ++i)
            out4[base + (size_t)i * 256] = z;
        return;
    }

    const int w    = tid >> 6;
    const int lane = tid & 63;
    const int n    = (b << 2) + w;

    __shared__ float esh[4][DD];
    esh[w][lane]      = embed[n * DD + lane];
    esh[w][lane + 64] = embed[n * DD + 64 + lane];
    __syncthreads();

    float at = 0.f, ab = 0.f;
#pragma unroll 8
    for (int k = 0; k < DD; ++k) {
        float ek = esh[w][k];
        at = fmaf(ek, W1[k * HH + lane],        at);   // 256 B coalesced row
        ab = fmaf(ek, W1[(DD + k) * HH + lane], ab);
    }
    Pt[n * HH + lane] = at;
    Pb[n * HH + lane] = ab;
}

// Fused gate+scatter: 16 edges per wave, 4 per 16-lane group, unrolled x4.
// adj[r][c] == 1.0 by construction for every listed edge -> no adj read on
// the direct term; transpose term reads adj[c][r] (issued EARLY, hides under
// the gather+reduce chain) and skips the atomic when zero (~99.6%).
__global__ void edge_kernel(const float4* __restrict__ Pt4,
                            const float4* __restrict__ Pb4,
                            const float* __restrict__ b1,
                            const float* __restrict__ W2,
                            const float* __restrict__ b2,
                            const float* __restrict__ noise,
                            const int* __restrict__ ei,
                            const float* __restrict__ adj,
                            float* __restrict__ out) {
    const int tid  = threadIdx.x;
    const int lane = tid & 63;
    const int q    = lane & 15;                       // hidden quad 0..15
    const int g16  = lane >> 4;                       // group in wave (0..3)

    // Per-block layout detect: int64 edge_index has all-zero high words.
    __shared__ int sflag;
    if (tid < 64) {
        int v = ei[2 * tid + 1];
        unsigned long long bal = __ballot(v != 0);
        if (tid == 0) sflag = (bal == 0ULL) ? 1 : 0;
    }
    __syncthreads();
    const bool i64 = (sflag != 0);

    const int wav   = (blockIdx.x << 2) + (tid >> 6);
    const int ebase = wav * EPW + g16 * 4;

    int r[4], c[4];
    if (i64) {
        const int4 r0 = ((const int4*)ei)[(ebase >> 1)];
        const int4 r1 = ((const int4*)ei)[(ebase >> 1) + 1];
        const int4 c0 = ((const int4*)(ei + 2 * EE))[(ebase >> 1)];
        const int4 c1 = ((const int4*)(ei + 2 * EE))[(ebase >> 1) + 1];
        r[0] = r0.x; r[1] = r0.z; r[2] = r1.x; r[3] = r1.z;
        c[0] = c0.x; c[1] = c0.z; c[2] = c1.x; c[3] = c1.z;
    } else {
        const int4 rr = ((const int4*)ei)[ebase >> 2];
        const int4 cc = ((const int4*)(ei + EE))[ebase >> 2];
        r[0] = rr.x; r[1] = rr.y; r[2] = rr.z; r[3] = rr.w;
        c[0] = cc.x; c[1] = cc.y; c[2] = cc.z; c[3] = cc.w;
    }

    // Leaders issue the slow random loads EARLY (hide under gather+reduce).
    float u[4], a[4];
    if (q == 0) {
        const float4 un = ((const float4*)noise)[ebase >> 2];
        u[0] = un.x; u[1] = un.y; u[2] = un.z; u[3] = un.w;
#pragma unroll
        for (int i = 0; i < 4; ++i)
            a[i] = adj[(size_t)c[i] * NN + r[i]];
    }

    const float4 bb = ((const float4*)b1)[q];
    const float4 ww = ((const float4*)W2)[q];

    float v[4];
#pragma unroll
    for (int i = 0; i < 4; ++i) {
        const float4 pt = Pt4[r[i] * 16 + q];
        const float4 pb = Pb4[c[i] * 16 + q];
        v[i] = fmaxf(pt.x + pb.x + bb.x, 0.f) * ww.x
             + fmaxf(pt.y + pb.y + bb.y, 0.f) * ww.y
             + fmaxf(pt.z + pb.z + bb.z, 0.f) * ww.z
             + fmaxf(pt.w + pb.w + bb.w, 0.f) * ww.w;
    }

#pragma unroll
    for (int i = 0; i < 4; ++i)
#pragma unroll
        for (int off = 8; off; off >>= 1)
            v[i] += __shfl_xor(v[i], off, 64);

    if (q == 0) {                                     // 4 leader lanes per wave
        const float bias2 = b2[0];
#pragma unroll
        for (int i = 0; i < 4; ++i) {
            const float la = v[i] + bias2;
            // sigmoid(log u - log1p(-u) + la) = u / (u + (1-u) e^{-la})
            const float ex = __expf(-la);
            const float g2 = 0.5f * u[i] / (u[i] + (1.f - u[i]) * ex);
            atomicAdd(&out[(size_t)r[i] * NN + c[i]], g2);       // adj==1 here
            if (a[i] != 0.f)
                atomicAdd(&out[(size_t)c[i] * NN + r[i]], g2 * a[i]);
        }
    }
}

extern "C" void kernel_launch(void* const* d_in, const int* in_sizes, int n_in,
                              void* d_out, int out_size, void* d_ws, size_t ws_size,
                              hipStream_t stream) {
    const float* embed = (const float*)d_in[0];
    const float* adj   = (const float*)d_in[1];
    const float* noise = (const float*)d_in[2];
    const float* W1    = (const float*)d_in[3];
    const float* b1    = (const float*)d_in[4];
    const float* W2    = (const float*)d_in[5];
    const float* b2    = (const float*)d_in[6];
    const int*   ei    = (const int*)d_in[7];
    float* out = (float*)d_out;

    float* Pt = (float*)d_ws;                          // 2 MB
    float* Pb = Pt + (size_t)NN * HH;                  // 2 MB

    init_kernel<<<PRE_BLOCKS + FILL_BLOCKS, 256, 0, stream>>>(
        embed, W1, Pt, Pb, (float4*)out);
    edge_kernel<<<EE / (EPW * 4), 256, 0, stream>>>(
        (const float4*)Pt, (const float4*)Pb, b1, W2, b2, noise, ei, adj, out);
}